// Round 1
// baseline (874.402 us; speedup 1.0000x reference)
//
#include <hip/hip_runtime.h>

#define N_PTS 4096
#define B_SZ  8
#define M_OUT 1024
#define NS    64
#define CIN   128
#define COUT  256
// Worker blocks. Total grid = 8 + NW = 504 <= guaranteed residency capacity:
// LDS 53.76KB -> >=2 blocks/CU (3 fits: 3*53760=161280 <= 163840), 256 CUs ->
// >=512 slots. Every block is resident regardless of dispatch order, so the
// producer->consumer spin below cannot deadlock (no ordering assumption).
#define NW    496

typedef float v2f __attribute__((ext_vector_type(2)));

// Wave-64 max reduce via DPP (row_shr 1/2/4/8, bcast15, bcast31), result
// broadcast through readlane(63). Bit-exact fmax tree. HW-VALIDATED (v2 776us,
// R6 738us, R8/R9 726us passing runs).
__device__ __forceinline__ float dpp_max_f32(float v) {
  int x = __builtin_bit_cast(int, v);
#define STG(C)                                                              \
  {                                                                         \
    int y = __builtin_amdgcn_update_dpp(x, x, C, 0xF, 0xF, false);          \
    float a = __builtin_bit_cast(float, x);                                 \
    float b2 = __builtin_bit_cast(float, y);                                \
    a = fmaxf(a, b2);                                                       \
    x = __builtin_bit_cast(int, a);                                         \
  }
  STG(0x111) STG(0x112) STG(0x114) STG(0x118) STG(0x142) STG(0x143)
#undef STG
  return __builtin_bit_cast(float, __builtin_amdgcn_readlane(x, 63));
}

// ---------------------------------------------------------------------------
// Single persistent kernel:
//   blocks 0..7   : FPS (R6/R9-validated loop, byte-identical math) +
//                   progressive publication of indices every 64 steps via
//                   agent-scope release store to gprog[b]. s_setprio(3)
//                   protects the serial critical path from co-resident
//                   worker issue pressure.
//   blocks 8..503 : grid-stride conv tiles (R8-validated math), then
//                   release-add gdone; then grid-stride ballq+pool tiles,
//                   each gated on an acquire spin of gprog[b] (overlapping
//                   ~110us of ballq work under the 726us FPS window that
//                   previously ran at 2.4% occupancy).
// Cross-XCD visibility: producers publish with agent-scope release (drains
// vmcnt wave-wide, writes back XCD L2); consumers acquire + agent fence
// (invalidates L1/L2) before reading fps_idx / Z.  (Guideline 16.)
// ---------------------------------------------------------------------------
__global__ __launch_bounds__(256) void fused_kernel(
    const float* __restrict__ xyz, int* __restrict__ fps_idx,
    int* __restrict__ gprog, int* __restrict__ gdone,
    const float* __restrict__ F, const float* __restrict__ W,
    float* __restrict__ Z, const float* __restrict__ bias,
    const float* __restrict__ gamma, const float* __restrict__ beta,
    const float* __restrict__ rmean, const float* __restrict__ rvar,
    float* __restrict__ out) {
  __shared__ __align__(16) float smem[13360];
  if (blockIdx.x < 8) {
#pragma clang fp contract(off)
    __builtin_amdgcn_s_setprio(3);  // FPS is THE critical path (726us serial)
    // ---- FPS (R6-validated; math/order untouched) ----
    float* lx = smem;                         // [4096]
    float* ly = smem + 4096;                  // [4096]
    float* lz = smem + 8192;                  // [4096]
    float4 (*sl)[4] = (float4(*)[4])(smem + 12288);  // [2][4]
    int (*siw)[4] = (int(*)[4])(smem + 12320);       // [2][4]
    int* wlds = (int*)(smem + 12328);                // [1024]
    const int b = blockIdx.x, t = threadIdx.x;
    const int lane = t & 63, wv = t >> 6;
    const float* base = xyz + b * N_PTS * 3;
    for (int e = t; e < N_PTS; e += 256) {
      lx[e] = base[e * 3 + 0];
      ly[e] = base[e * 3 + 1];
      lz[e] = base[e * 3 + 2];
    }
    __syncthreads();
    const int nb = t * 16;  // contiguous: thread t owns [16t, 16t+16)
    v2f px[8], py[8], pz[8], m2[8];
#pragma unroll
    for (int j = 0; j < 8; ++j) {
      int n0 = nb + 2 * j;
      px[j] = (v2f){lx[n0], lx[n0 + 1]};
      py[j] = (v2f){ly[n0], ly[n0 + 1]};
      pz[j] = (v2f){lz[n0], lz[n0 + 1]};
      m2[j] = (v2f){1e10f, 1e10f};
    }
    int cur = 0;
    float cx = lx[0], cy = ly[0], cz = lz[0];
    for (int i = 0; i < M_OUT; ++i) {
      if (t == 0) wlds[i] = cur;
      float bv = -1.0f;
      int bj = 0;
#pragma unroll
      for (int j = 0; j < 8; ++j) {
        v2f dx = px[j] - cx, dy = py[j] - cy, dz = pz[j] - cz;
        v2f d = dx * dx + dy * dy;  // contract(off): numpy op order, no FMA
        d = d + dz * dz;
        v2f md = __builtin_elementwise_min(m2[j], d);
        m2[j] = md;
        // ascending j, strict > => lowest tied index within the thread
        if (md.x > bv) { bv = md.x; bj = 2 * j; }
        if (md.y > bv) { bv = md.y; bj = 2 * j + 1; }
      }
      const float mv = dpp_max_f32(bv);  // wave max, all lanes (validated)
      unsigned long long tied = __ballot(bv == mv);  // non-empty
      const int fl = __ffsll(tied) - 1;              // first tied lane
      const int bi = nb + bj;
      const int widx = __builtin_amdgcn_readlane(bi, fl);
      // Pre-barrier uniform LDS broadcast read; hides in barrier skew.
      const float wx = lx[widx], wy = ly[widx], wz = lz[widx];
      const int p = i & 1;
      if (lane == 0) {
        sl[p][wv] = make_float4(mv, wx, wy, wz);
        siw[p][wv] = widx;
      }
      __syncthreads();  // the only barrier per step (parity-buffered slots)
      float4 s0 = sl[p][0], s1 = sl[p][1], s2 = sl[p][2], s3 = sl[p][3];
      int i0 = siw[p][0], i1 = siw[p][1], i2 = siw[p][2], i3 = siw[p][3];
      float gv = s0.x, gx = s0.y, gy = s0.z, gz = s0.w;
      int gi = i0;
      bool bt;
      bt = (s1.x > gv) || (s1.x == gv && i1 < gi);
      if (bt) { gv = s1.x; gi = i1; gx = s1.y; gy = s1.z; gz = s1.w; }
      bt = (s2.x > gv) || (s2.x == gv && i2 < gi);
      if (bt) { gv = s2.x; gi = i2; gx = s2.y; gy = s2.z; gz = s2.w; }
      bt = (s3.x > gv) || (s3.x == gv && i3 < gi);
      if (bt) { gv = s3.x; gi = i3; gx = s3.y; gy = s3.z; gz = s3.w; }
      cur = gi; cx = gx; cy = gy; cz = gz;
      // ---- progressive publish: 64-index chunk, every 64 steps (16x) ----
      // wlds[cb..cb+63] final (last one written at top of this iteration,
      // same wave). Wave-0 stores + lane-0 agent release: the release's
      // vmcnt(0) drain is per-WAVE, covering all 64 lanes' stores; the
      // writeback makes them cross-XCD visible before gprog updates.
      if ((i & 63) == 63 && wv == 0) {
        const int cb = i & ~63;
        fps_idx[b * M_OUT + cb + lane] = wlds[cb + lane];
        if (lane == 0)
          __hip_atomic_store(gprog + b, i + 1, __ATOMIC_RELEASE,
                             __HIP_MEMORY_SCOPE_AGENT);
      }
    }
    // (final flush removed: all 16 chunks published in-loop)
  } else {
    const int w = blockIdx.x - 8;  // 0..NW-1
    // ---- phase A: conv tiles, grid-stride (R8-validated math) ----
    // Z[b][n][o] = sum_c F[b][c][n] * W[o][c]
    {
      float (*Bs)[68] = (float(*)[68])smem;          // [128][68]
      float (*As)[68] = (float(*)[68])(smem + 8704); // [32][68]
      const int tid = threadIdx.x;
      const int tx = tid & 15, ty = tid >> 4;
      for (int tile = w; tile < 2048; tile += NW) {
        __syncthreads();  // prev tile's As/Bs readers done before refill
        const int n0 = (tile & 63) * 64;
        const int o0 = ((tile >> 6) & 3) * 64;
        const int bb = tile >> 8;
        for (int l = 0; l < 32; ++l) {
          int e = l * 256 + tid;
          int c = e & 127, oo = e >> 7;
          Bs[c][oo] = W[(o0 + oo) * CIN + c];
        }
        float acc[4][4] = {};
        const float* Fb = F + bb * CIN * N_PTS;
        for (int c0 = 0; c0 < CIN; c0 += 32) {
          __syncthreads();
          for (int l = 0; l < 8; ++l) {
            int e = l * 256 + tid;
            int nn = e & 63, cc = e >> 6;
            As[cc][nn] = Fb[(c0 + cc) * N_PTS + n0 + nn];
          }
          __syncthreads();
#pragma unroll
          for (int cc = 0; cc < 32; ++cc) {
            float4 a = *(const float4*)&As[cc][tx * 4];
            float4 w4 = *(const float4*)&Bs[c0 + cc][ty * 4];
            acc[0][0] += a.x * w4.x; acc[0][1] += a.x * w4.y; acc[0][2] += a.x * w4.z; acc[0][3] += a.x * w4.w;
            acc[1][0] += a.y * w4.x; acc[1][1] += a.y * w4.y; acc[1][2] += a.y * w4.z; acc[1][3] += a.y * w4.w;
            acc[2][0] += a.z * w4.x; acc[2][1] += a.z * w4.y; acc[2][2] += a.z * w4.z; acc[2][3] += a.z * w4.w;
            acc[3][0] += a.w * w4.x; acc[3][1] += a.w * w4.y; acc[3][2] += a.w * w4.z; acc[3][3] += a.w * w4.w;
          }
        }
        float* Zb = Z + (size_t)(bb * N_PTS + n0) * COUT + o0;
#pragma unroll
        for (int i2 = 0; i2 < 4; ++i2) {
          int nn = tx * 4 + i2;
          float4 v = make_float4(acc[i2][0], acc[i2][1], acc[i2][2], acc[i2][3]);
          *(float4*)&Zb[(size_t)nn * COUT + ty * 4] = v;
        }
      }
    }
    // All 4 waves' Z stores drained by the barrier's per-wave vmcnt(0);
    // lane-0 release-add then makes them agent-visible.
    __syncthreads();
    if (threadIdx.x == 0)
      __hip_atomic_fetch_add(gdone, 1, __ATOMIC_RELEASE,
                             __HIP_MEMORY_SCOPE_AGENT);
    // ---- phase B: ballq + gather/max/BN/ReLU tiles, grid-stride ----
    // Wait for all conv producers (Z complete), then per-tile for FPS
    // progress. Spinner = wave0 lane0 with s_sleep; block parked at barrier.
    if (threadIdx.x == 0) {
      while (__hip_atomic_load(gdone, __ATOMIC_ACQUIRE,
                               __HIP_MEMORY_SCOPE_AGENT) < NW)
        __builtin_amdgcn_s_sleep(16);
    }
    __syncthreads();
    __builtin_amdgcn_fence(__ATOMIC_ACQUIRE, "agent");  // Z now coherent
    const int lane = threadIdx.x & 63, wv = threadIdx.x >> 6;
    const int o = threadIdx.x;  // 0..255
    const float sc = gamma[o] * (1.0f / sqrtf(rvar[o] + 1e-5f));
    const float bo = bias[o], mo = rmean[o], bt = beta[o];
    float (*T)[9] = (float(*)[9])smem;        // [256][9]
    int* sidx = (int*)(smem + 2304);          // [8*NS]
    for (int tb = w; tb < 1024; tb += NW) {
      const int b = tb & 7;
      const int m0 = (tb >> 3) * 8;
      if (threadIdx.x == 0) {
        while (__hip_atomic_load(gprog + b, __ATOMIC_ACQUIRE,
                                 __HIP_MEMORY_SCOPE_AGENT) < m0 + 8)
          __builtin_amdgcn_s_sleep(16);
      }
      __syncthreads();  // also orders prev tile's T readers vs sidx writers
      __builtin_amdgcn_fence(__ATOMIC_ACQUIRE, "agent");  // fps_idx coherent
      const float* base = xyz + b * N_PTS * 3;
      // ---- ball query: 2 centers per wave (validated scan, per-center) ----
      {
#pragma clang fp contract(off)
        for (int c = wv; c < 8; c += 4) {
          const int cidx = fps_idx[b * M_OUT + m0 + c];
          const float cx = base[cidx * 3 + 0], cy = base[cidx * 3 + 1],
                      cz = base[cidx * 3 + 2];
          int* srow = sidx + c * NS;
          int cnt = 0, first = 0;
          for (int ch = 0; ch < N_PTS / 64 && cnt < NS; ++ch) {
            const int n = ch * 64 + lane;
            float dx = base[n * 3 + 0] - cx;
            float dy = base[n * 3 + 1] - cy;
            float dz = base[n * 3 + 2] - cz;
            float d = dx * dx + dy * dy;
            d = d + dz * dz;
            const bool inb = d < 0.1024f;  // f32(RADIUS^2)
            unsigned long long mask = __ballot(inb);
            if (cnt == 0 && mask) first = ch * 64 + (__ffsll(mask) - 1);
            const int pos = cnt + __popcll(mask & ((1ull << lane) - 1ull));
            if (inb && pos < NS) srow[pos] = n;
            cnt += (int)__popcll(mask);
          }
          if (lane >= cnt) srow[lane] = first;  // pad (center => cnt >= 1)
        }
      }
      __syncthreads();
      // ---- gather + max-pool + BN + ReLU (8 chains; fmax order preserved) --
      const float* Zb = Z + (size_t)b * N_PTS * COUT;
      for (int mi = 0; mi < 8; ++mi) {
        float c0 = -1e30f, c1 = -1e30f, c2 = -1e30f, c3 = -1e30f;
        float c4 = -1e30f, c5 = -1e30f, c6 = -1e30f, c7 = -1e30f;
#pragma unroll
        for (int s = 0; s < NS; s += 8) {
          int4 iv0 = *(const int4*)&sidx[mi * NS + s];
          int4 iv1 = *(const int4*)&sidx[mi * NS + s + 4];
          c0 = fmaxf(c0, Zb[(size_t)iv0.x * COUT + o]);
          c1 = fmaxf(c1, Zb[(size_t)iv0.y * COUT + o]);
          c2 = fmaxf(c2, Zb[(size_t)iv0.z * COUT + o]);
          c3 = fmaxf(c3, Zb[(size_t)iv0.w * COUT + o]);
          c4 = fmaxf(c4, Zb[(size_t)iv1.x * COUT + o]);
          c5 = fmaxf(c5, Zb[(size_t)iv1.y * COUT + o]);
          c6 = fmaxf(c6, Zb[(size_t)iv1.z * COUT + o]);
          c7 = fmaxf(c7, Zb[(size_t)iv1.w * COUT + o]);
        }
        float best = fmaxf(fmaxf(fmaxf(c0, c1), fmaxf(c2, c3)),
                           fmaxf(fmaxf(c4, c5), fmaxf(c6, c7)));
        float tv = best + bo;
        tv = (tv - mo) * sc + bt;
        T[o][mi] = fmaxf(tv, 0.0f);  // distinct (o,mi) per thread: race-free
      }
      __syncthreads();
      for (int l = 0; l < 8; ++l) {
        int e = l * 256 + (int)threadIdx.x;
        int mm = e & 7, oo = e >> 3;
        out[(size_t)(b * COUT + oo) * M_OUT + m0 + mm] = T[oo][mm];
      }
    }
  }
}

extern "C" void kernel_launch(void* const* d_in, const int* in_sizes, int n_in,
                              void* d_out, int out_size, void* d_ws, size_t ws_size,
                              hipStream_t stream) {
  const float* xyz      = (const float*)d_in[0];
  const float* features = (const float*)d_in[1];
  const float* W        = (const float*)d_in[2];
  const float* bias     = (const float*)d_in[3];
  const float* gamma    = (const float*)d_in[4];
  const float* beta     = (const float*)d_in[5];
  const float* rmean    = (const float*)d_in[6];
  const float* rvar     = (const float*)d_in[7];
  float* out = (float*)d_out;

  char* ws = (char*)d_ws;
  int* fps   = (int*)ws;                                 // 32 KB
  int* flags = (int*)(ws + (48 << 10));                  // gprog[8], gdone[1]
  float* Z   = (float*)(ws + (64 << 10) + (2 << 20));    // 33.5 MB

  // Reset sync flags every run (graph replays re-execute this memset, so no
  // stale-progress hazard even if the workspace is poisoned between runs).
  hipMemsetAsync(flags, 0, 64, stream);
  fused_kernel<<<8 + NW, 256, 0, stream>>>(
      xyz, fps, flags, flags + 8, features, W, Z, bias, gamma, beta, rmean,
      rvar, out);
}

// Round 2
// 812.522 us; speedup vs baseline: 1.0762x; 1.0762x over previous
//
#include <hip/hip_runtime.h>

#define N_PTS 4096
#define B_SZ  8
#define M_OUT 1024
#define NS    64
#define CIN   128
#define COUT  256
// Worker blocks. Total grid = 8 + NW = 504 <= guaranteed residency capacity:
// LDS 53.76KB -> 3 blocks/CU fit (3*53760 <= 163840), 256 CUs -> >=512 slots.
// Every block is resident regardless of dispatch order, so the producer ->
// consumer polling below cannot deadlock (no ordering assumption).
#define NW    496

typedef float v2f __attribute__((ext_vector_type(2)));

// Wave-64 max reduce via DPP (row_shr 1/2/4/8, bcast15, bcast31), result
// broadcast through readlane(63). Bit-exact fmax tree. HW-VALIDATED (v2 776us,
// R6 738us, R8/R9 726us passing runs).
__device__ __forceinline__ float dpp_max_f32(float v) {
  int x = __builtin_bit_cast(int, v);
#define STG(C)                                                              \
  {                                                                         \
    int y = __builtin_amdgcn_update_dpp(x, x, C, 0xF, 0xF, false);          \
    float a = __builtin_bit_cast(float, x);                                 \
    float b2 = __builtin_bit_cast(float, y);                                \
    a = fmaxf(a, b2);                                                       \
    x = __builtin_bit_cast(int, a);                                         \
  }
  STG(0x111) STG(0x112) STG(0x114) STG(0x118) STG(0x142) STG(0x143)
#undef STG
  return __builtin_bit_cast(float, __builtin_amdgcn_readlane(x, 63));
}

// ---------------------------------------------------------------------------
// Single persistent kernel, R1-postmortem revision.
//
// R1 regression root cause (counters: dur 726->814us, FETCH +6.9MB): agent
// RELEASE fences on the FPS critical path forced s_waitcnt+L2-WRITEBACK per
// publish (L2s full of dirty conv Z -> multi-us stalls of wave 0, 16x), and
// per-tile agent ACQUIRE fences on consumers INVALIDATED the XCD L2 1024x,
// destroying xyz/Z gather locality.
//
// Fix: NO fences anywhere near the critical path. fps_idx itself is the
// synchronization variable: pre-set to -1, published per-step by thread 0 via
// RELAXED agent-scope atomic store (sc1: write-through to the coherent
// Infinity Cache, bypassing the non-coherent XCD L2; fire-and-forget, no
// waitcnt). Consumers poll the 8 needed entries with RELAXED agent-scope
// atomic loads (sc1 reads from MALL; no cache invalidation side effects, so
// ordinary xyz/Z loads stay L2-hot). Data-as-flag => no ordering fence needed.
// Z coherence still uses the ONE-TIME gdone release/acquire (off the FPS
// critical path; validated in R1).
// ---------------------------------------------------------------------------
__global__ __launch_bounds__(256) void fused_kernel(
    const float* __restrict__ xyz, int* __restrict__ fps_idx,
    int* __restrict__ gdone, const float* __restrict__ F,
    const float* __restrict__ W, float* __restrict__ Z,
    const float* __restrict__ bias, const float* __restrict__ gamma,
    const float* __restrict__ beta, const float* __restrict__ rmean,
    const float* __restrict__ rvar, float* __restrict__ out) {
  __shared__ __align__(16) float smem[13360];
  if (blockIdx.x < 8) {
#pragma clang fp contract(off)
    __builtin_amdgcn_s_setprio(3);  // FPS is THE critical path (726us serial)
    // ---- FPS (R6-validated; math/order untouched) ----
    float* lx = smem;                         // [4096]
    float* ly = smem + 4096;                  // [4096]
    float* lz = smem + 8192;                  // [4096]
    float4 (*sl)[4] = (float4(*)[4])(smem + 12288);  // [2][4]
    int (*siw)[4] = (int(*)[4])(smem + 12320);       // [2][4]
    const int b = blockIdx.x, t = threadIdx.x;
    const int lane = t & 63, wv = t >> 6;
    const float* base = xyz + b * N_PTS * 3;
    for (int e = t; e < N_PTS; e += 256) {
      lx[e] = base[e * 3 + 0];
      ly[e] = base[e * 3 + 1];
      lz[e] = base[e * 3 + 2];
    }
    __syncthreads();
    const int nb = t * 16;  // contiguous: thread t owns [16t, 16t+16)
    v2f px[8], py[8], pz[8], m2[8];
#pragma unroll
    for (int j = 0; j < 8; ++j) {
      int n0 = nb + 2 * j;
      px[j] = (v2f){lx[n0], lx[n0 + 1]};
      py[j] = (v2f){ly[n0], ly[n0 + 1]};
      pz[j] = (v2f){lz[n0], lz[n0 + 1]};
      m2[j] = (v2f){1e10f, 1e10f};
    }
    int cur = 0;
    float cx = lx[0], cy = ly[0], cz = lz[0];
    for (int i = 0; i < M_OUT; ++i) {
      // Progressive publish: relaxed agent atomic (sc1 -> MALL, coherent
      // cross-XCD). Fire-and-forget: no waitcnt, no fence, no L2 writeback.
      // One store per ~1600-cyc step retires long before vmcnt backpressure.
      if (t == 0)
        __hip_atomic_store(fps_idx + b * M_OUT + i, cur, __ATOMIC_RELAXED,
                           __HIP_MEMORY_SCOPE_AGENT);
      float bv = -1.0f;
      int bj = 0;
#pragma unroll
      for (int j = 0; j < 8; ++j) {
        v2f dx = px[j] - cx, dy = py[j] - cy, dz = pz[j] - cz;
        v2f d = dx * dx + dy * dy;  // contract(off): numpy op order, no FMA
        d = d + dz * dz;
        v2f md = __builtin_elementwise_min(m2[j], d);
        m2[j] = md;
        // ascending j, strict > => lowest tied index within the thread
        if (md.x > bv) { bv = md.x; bj = 2 * j; }
        if (md.y > bv) { bv = md.y; bj = 2 * j + 1; }
      }
      const float mv = dpp_max_f32(bv);  // wave max, all lanes (validated)
      unsigned long long tied = __ballot(bv == mv);  // non-empty
      const int fl = __ffsll(tied) - 1;              // first tied lane
      const int bi = nb + bj;
      const int widx = __builtin_amdgcn_readlane(bi, fl);
      // Pre-barrier uniform LDS broadcast read; hides in barrier skew.
      const float wx = lx[widx], wy = ly[widx], wz = lz[widx];
      const int p = i & 1;
      if (lane == 0) {
        sl[p][wv] = make_float4(mv, wx, wy, wz);
        siw[p][wv] = widx;
      }
      __syncthreads();  // the only barrier per step (parity-buffered slots)
      float4 s0 = sl[p][0], s1 = sl[p][1], s2 = sl[p][2], s3 = sl[p][3];
      int i0 = siw[p][0], i1 = siw[p][1], i2 = siw[p][2], i3 = siw[p][3];
      float gv = s0.x, gx = s0.y, gy = s0.z, gz = s0.w;
      int gi = i0;
      bool bt;
      bt = (s1.x > gv) || (s1.x == gv && i1 < gi);
      if (bt) { gv = s1.x; gi = i1; gx = s1.y; gy = s1.z; gz = s1.w; }
      bt = (s2.x > gv) || (s2.x == gv && i2 < gi);
      if (bt) { gv = s2.x; gi = i2; gx = s2.y; gy = s2.z; gz = s2.w; }
      bt = (s3.x > gv) || (s3.x == gv && i3 < gi);
      if (bt) { gv = s3.x; gi = i3; gx = s3.y; gy = s3.z; gz = s3.w; }
      cur = gi; cx = gx; cy = gy; cz = gz;
    }
  } else {
    const int w = blockIdx.x - 8;  // 0..NW-1
    // ---- phase A: conv tiles, grid-stride (R8-validated math) ----
    // Z[b][n][o] = sum_c F[b][c][n] * W[o][c]
    {
      float (*Bs)[68] = (float(*)[68])smem;          // [128][68]
      float (*As)[68] = (float(*)[68])(smem + 8704); // [32][68]
      const int tid = threadIdx.x;
      const int tx = tid & 15, ty = tid >> 4;
      for (int tile = w; tile < 2048; tile += NW) {
        __syncthreads();  // prev tile's As/Bs readers done before refill
        const int n0 = (tile & 63) * 64;
        const int o0 = ((tile >> 6) & 3) * 64;
        const int bb = tile >> 8;
        for (int l = 0; l < 32; ++l) {
          int e = l * 256 + tid;
          int c = e & 127, oo = e >> 7;
          Bs[c][oo] = W[(o0 + oo) * CIN + c];
        }
        float acc[4][4] = {};
        const float* Fb = F + bb * CIN * N_PTS;
        for (int c0 = 0; c0 < CIN; c0 += 32) {
          __syncthreads();
          for (int l = 0; l < 8; ++l) {
            int e = l * 256 + tid;
            int nn = e & 63, cc = e >> 6;
            As[cc][nn] = Fb[(c0 + cc) * N_PTS + n0 + nn];
          }
          __syncthreads();
#pragma unroll
          for (int cc = 0; cc < 32; ++cc) {
            float4 a = *(const float4*)&As[cc][tx * 4];
            float4 w4 = *(const float4*)&Bs[c0 + cc][ty * 4];
            acc[0][0] += a.x * w4.x; acc[0][1] += a.x * w4.y; acc[0][2] += a.x * w4.z; acc[0][3] += a.x * w4.w;
            acc[1][0] += a.y * w4.x; acc[1][1] += a.y * w4.y; acc[1][2] += a.y * w4.z; acc[1][3] += a.y * w4.w;
            acc[2][0] += a.z * w4.x; acc[2][1] += a.z * w4.y; acc[2][2] += a.z * w4.z; acc[2][3] += a.z * w4.w;
            acc[3][0] += a.w * w4.x; acc[3][1] += a.w * w4.y; acc[3][2] += a.w * w4.z; acc[3][3] += a.w * w4.w;
          }
        }
        float* Zb = Z + (size_t)(bb * N_PTS + n0) * COUT + o0;
#pragma unroll
        for (int i2 = 0; i2 < 4; ++i2) {
          int nn = tx * 4 + i2;
          float4 v = make_float4(acc[i2][0], acc[i2][1], acc[i2][2], acc[i2][3]);
          *(float4*)&Zb[(size_t)nn * COUT + ty * 4] = v;
        }
      }
    }
    // ONE-TIME Z handoff (off the FPS critical path): barrier drains each
    // wave's Z stores (vmcnt(0)); release-add writes back this XCD's L2 so Z
    // is agent-visible; consumers below acquire-invalidate ONCE.
    __syncthreads();
    if (threadIdx.x == 0)
      __hip_atomic_fetch_add(gdone, 1, __ATOMIC_RELEASE,
                             __HIP_MEMORY_SCOPE_AGENT);
    if (threadIdx.x == 0) {
      while (__hip_atomic_load(gdone, __ATOMIC_ACQUIRE,
                               __HIP_MEMORY_SCOPE_AGENT) < NW)
        __builtin_amdgcn_s_sleep(16);
    }
    __syncthreads();
    __builtin_amdgcn_fence(__ATOMIC_ACQUIRE, "agent");  // Z now coherent
    // ---- phase B: ballq + gather/max/BN/ReLU tiles, grid-stride ----
    // Per-tile gate: poll the 8 needed fps_idx entries (relaxed agent loads,
    // sc1 from MALL; NO fence, NO L2 invalidation -> xyz/Z stay L2-hot).
    const int lane = threadIdx.x & 63, wv = threadIdx.x >> 6;
    const int o = threadIdx.x;  // 0..255
    const float sc = gamma[o] * (1.0f / sqrtf(rvar[o] + 1e-5f));
    const float bo = bias[o], mo = rmean[o], bt = beta[o];
    float (*T)[9] = (float(*)[9])smem;        // [256][9] floats
    int* sidx = (int*)(smem + 2304);          // [8*NS]
    int* cctr = (int*)(smem + 2816);          // [8] center indices
    for (int tb = w; tb < 1024; tb += NW) {
      const int b = tb & 7;
      const int m0 = (tb >> 3) * 8;
      if (threadIdx.x == 0) {
        int got;
        do {
          got = 1;
#pragma unroll
          for (int c = 0; c < 8; ++c) {
            int v = __hip_atomic_load(fps_idx + b * M_OUT + m0 + c,
                                      __ATOMIC_RELAXED,
                                      __HIP_MEMORY_SCOPE_AGENT);
            cctr[c] = v;
            got &= (v != -1);
          }
          if (!got) __builtin_amdgcn_s_sleep(8);
        } while (!got);
      }
      __syncthreads();  // broadcast cctr; also orders prev tile's T/sidx reuse
      const float* base = xyz + b * N_PTS * 3;
      // ---- ball query: 2 centers per wave (validated scan, per-center) ----
      {
#pragma clang fp contract(off)
        for (int c = wv; c < 8; c += 4) {
          const int cidx = cctr[c];
          const float cx = base[cidx * 3 + 0], cy = base[cidx * 3 + 1],
                      cz = base[cidx * 3 + 2];
          int* srow = sidx + c * NS;
          int cnt = 0, first = 0;
          for (int ch = 0; ch < N_PTS / 64 && cnt < NS; ++ch) {
            const int n = ch * 64 + lane;
            float dx = base[n * 3 + 0] - cx;
            float dy = base[n * 3 + 1] - cy;
            float dz = base[n * 3 + 2] - cz;
            float d = dx * dx + dy * dy;
            d = d + dz * dz;
            const bool inb = d < 0.1024f;  // f32(RADIUS^2)
            unsigned long long mask = __ballot(inb);
            if (cnt == 0 && mask) first = ch * 64 + (__ffsll(mask) - 1);
            const int pos = cnt + __popcll(mask & ((1ull << lane) - 1ull));
            if (inb && pos < NS) srow[pos] = n;
            cnt += (int)__popcll(mask);
          }
          if (lane >= cnt) srow[lane] = first;  // pad (center => cnt >= 1)
        }
      }
      __syncthreads();
      // ---- gather + max-pool + BN + ReLU (8 chains; fmax order preserved) --
      const float* Zb = Z + (size_t)b * N_PTS * COUT;
      for (int mi = 0; mi < 8; ++mi) {
        float c0 = -1e30f, c1 = -1e30f, c2 = -1e30f, c3 = -1e30f;
        float c4 = -1e30f, c5 = -1e30f, c6 = -1e30f, c7 = -1e30f;
#pragma unroll
        for (int s = 0; s < NS; s += 8) {
          int4 iv0 = *(const int4*)&sidx[mi * NS + s];
          int4 iv1 = *(const int4*)&sidx[mi * NS + s + 4];
          c0 = fmaxf(c0, Zb[(size_t)iv0.x * COUT + o]);
          c1 = fmaxf(c1, Zb[(size_t)iv0.y * COUT + o]);
          c2 = fmaxf(c2, Zb[(size_t)iv0.z * COUT + o]);
          c3 = fmaxf(c3, Zb[(size_t)iv0.w * COUT + o]);
          c4 = fmaxf(c4, Zb[(size_t)iv1.x * COUT + o]);
          c5 = fmaxf(c5, Zb[(size_t)iv1.y * COUT + o]);
          c6 = fmaxf(c6, Zb[(size_t)iv1.z * COUT + o]);
          c7 = fmaxf(c7, Zb[(size_t)iv1.w * COUT + o]);
        }
        float best = fmaxf(fmaxf(fmaxf(c0, c1), fmaxf(c2, c3)),
                           fmaxf(fmaxf(c4, c5), fmaxf(c6, c7)));
        float tv = best + bo;
        tv = (tv - mo) * sc + bt;
        T[o][mi] = fmaxf(tv, 0.0f);  // distinct (o,mi) per thread: race-free
      }
      __syncthreads();
      for (int l = 0; l < 8; ++l) {
        int e = l * 256 + (int)threadIdx.x;
        int mm = e & 7, oo = e >> 3;
        out[(size_t)(b * COUT + oo) * M_OUT + m0 + mm] = T[oo][mm];
      }
    }
  }
}

extern "C" void kernel_launch(void* const* d_in, const int* in_sizes, int n_in,
                              void* d_out, int out_size, void* d_ws, size_t ws_size,
                              hipStream_t stream) {
  const float* xyz      = (const float*)d_in[0];
  const float* features = (const float*)d_in[1];
  const float* W        = (const float*)d_in[2];
  const float* bias     = (const float*)d_in[3];
  const float* gamma    = (const float*)d_in[4];
  const float* beta     = (const float*)d_in[5];
  const float* rmean    = (const float*)d_in[6];
  const float* rvar     = (const float*)d_in[7];
  float* out = (float*)d_out;

  char* ws = (char*)d_ws;
  int* fps   = (int*)ws;                                 // 32 KB
  int* flags = (int*)(ws + (48 << 10));                  // gdone[1]
  float* Z   = (float*)(ws + (64 << 10) + (2 << 20));    // 33.5 MB

  // fps_idx doubles as the producer->consumer flag array: -1 = not yet
  // published. Re-memset every launch (graph replays re-execute both).
  hipMemsetAsync(fps, 0xFF, 32 << 10, stream);
  hipMemsetAsync(flags, 0, 64, stream);
  fused_kernel<<<8 + NW, 256, 0, stream>>>(
      xyz, fps, flags, features, W, Z, bias, gamma, beta, rmean, rvar, out);
}

// Round 3
// 802.952 us; speedup vs baseline: 1.0890x; 1.0119x over previous
//
#include <hip/hip_runtime.h>

#define N_PTS 4096
#define B_SZ  8
#define M_OUT 1024
#define NS    64
#define CIN   128
#define COUT  256
// Worker blocks. Total grid = 8 + NW = 504 <= guaranteed residency capacity:
// LDS 53.76KB -> 3 blocks/CU fit (3*53760 <= 163840), 256 CUs -> >=512 slots.
// Every block is resident regardless of dispatch order, so the producer ->
// consumer polling below cannot deadlock (no ordering assumption).
#define NW    496
// Phase-B tiling: chunks 0..119 as 8-center tiles (960 tiles, all hidden
// under the FPS window), centers 960..1023 as SINGLE-center tiles (512
// tiles) so the endgame is latency-parallel: the final 64 centers (published
// in the last ~6us of FPS) are pooled by 64 blocks concurrently -> tail =
// ONE center's scan+pool (~5us), not a serial 8-center tile (~19us, R2).
#define NTILE_N 960
#define NTILE_T 1472

typedef float v2f __attribute__((ext_vector_type(2)));

// Wave-64 max reduce via DPP (row_shr 1/2/4/8, bcast15, bcast31), result
// broadcast through readlane(63). Bit-exact fmax tree. HW-VALIDATED (v2 776us,
// R6 738us, R8/R9 726us passing runs).
__device__ __forceinline__ float dpp_max_f32(float v) {
  int x = __builtin_bit_cast(int, v);
#define STG(C)                                                              \
  {                                                                         \
    int y = __builtin_amdgcn_update_dpp(x, x, C, 0xF, 0xF, false);          \
    float a = __builtin_bit_cast(float, x);                                 \
    float b2 = __builtin_bit_cast(float, y);                                \
    a = fmaxf(a, b2);                                                       \
    x = __builtin_bit_cast(int, a);                                         \
  }
  STG(0x111) STG(0x112) STG(0x114) STG(0x118) STG(0x142) STG(0x143)
#undef STG
  return __builtin_bit_cast(float, __builtin_amdgcn_readlane(x, 63));
}

// ---------------------------------------------------------------------------
// Single persistent kernel (R2-validated sync scheme: RELAXED agent-scope
// atomics to the coherent MALL as BOTH data and flag; zero fences on the FPS
// critical path; one-time gdone release/acquire for Z).
// R3 deltas: (a) dead final FPS step skipped (index 1023 publishes at top of
// step 1023; break before the unused distance pass), (b) endgame centers
// 960..1023 processed as single-center tiles for a ~5us tail, (c) gdone
// folded into the 0xFF-memset region (init -1, full count = NW-1) so the
// launch needs ONE memset node instead of two.
// ---------------------------------------------------------------------------
__global__ __launch_bounds__(256) void fused_kernel(
    const float* __restrict__ xyz, int* __restrict__ fps_idx,
    int* __restrict__ gdone, const float* __restrict__ F,
    const float* __restrict__ W, float* __restrict__ Z,
    const float* __restrict__ bias, const float* __restrict__ gamma,
    const float* __restrict__ beta, const float* __restrict__ rmean,
    const float* __restrict__ rvar, float* __restrict__ out) {
  __shared__ __align__(16) float smem[13360];
  if (blockIdx.x < 8) {
#pragma clang fp contract(off)
    __builtin_amdgcn_s_setprio(3);  // FPS is THE critical path (726us serial)
    // ---- FPS (R6-validated; math/order untouched) ----
    float* lx = smem;                         // [4096]
    float* ly = smem + 4096;                  // [4096]
    float* lz = smem + 8192;                  // [4096]
    float4 (*sl)[4] = (float4(*)[4])(smem + 12288);  // [2][4]
    int (*siw)[4] = (int(*)[4])(smem + 12320);       // [2][4]
    const int b = blockIdx.x, t = threadIdx.x;
    const int lane = t & 63, wv = t >> 6;
    const float* base = xyz + b * N_PTS * 3;
    for (int e = t; e < N_PTS; e += 256) {
      lx[e] = base[e * 3 + 0];
      ly[e] = base[e * 3 + 1];
      lz[e] = base[e * 3 + 2];
    }
    __syncthreads();
    const int nb = t * 16;  // contiguous: thread t owns [16t, 16t+16)
    v2f px[8], py[8], pz[8], m2[8];
#pragma unroll
    for (int j = 0; j < 8; ++j) {
      int n0 = nb + 2 * j;
      px[j] = (v2f){lx[n0], lx[n0 + 1]};
      py[j] = (v2f){ly[n0], ly[n0 + 1]};
      pz[j] = (v2f){lz[n0], lz[n0 + 1]};
      m2[j] = (v2f){1e10f, 1e10f};
    }
    int cur = 0;
    float cx = lx[0], cy = ly[0], cz = lz[0];
    for (int i = 0; i < M_OUT; ++i) {
      // Progressive publish: relaxed agent atomic (sc1 -> MALL, coherent
      // cross-XCD). Fire-and-forget: no waitcnt, no fence, no L2 writeback.
      if (t == 0)
        __hip_atomic_store(fps_idx + b * M_OUT + i, cur, __ATOMIC_RELAXED,
                           __HIP_MEMORY_SCOPE_AGENT);
      if (i == M_OUT - 1) break;  // last index published; its distance pass
                                  // is dead work (would only compute idx 1024)
      float bv = -1.0f;
      int bj = 0;
#pragma unroll
      for (int j = 0; j < 8; ++j) {
        v2f dx = px[j] - cx, dy = py[j] - cy, dz = pz[j] - cz;
        v2f d = dx * dx + dy * dy;  // contract(off): numpy op order, no FMA
        d = d + dz * dz;
        v2f md = __builtin_elementwise_min(m2[j], d);
        m2[j] = md;
        // ascending j, strict > => lowest tied index within the thread
        if (md.x > bv) { bv = md.x; bj = 2 * j; }
        if (md.y > bv) { bv = md.y; bj = 2 * j + 1; }
      }
      const float mv = dpp_max_f32(bv);  // wave max, all lanes (validated)
      unsigned long long tied = __ballot(bv == mv);  // non-empty
      const int fl = __ffsll(tied) - 1;              // first tied lane
      const int bi = nb + bj;
      const int widx = __builtin_amdgcn_readlane(bi, fl);
      // Pre-barrier uniform LDS broadcast read; hides in barrier skew.
      const float wx = lx[widx], wy = ly[widx], wz = lz[widx];
      const int p = i & 1;
      if (lane == 0) {
        sl[p][wv] = make_float4(mv, wx, wy, wz);
        siw[p][wv] = widx;
      }
      __syncthreads();  // the only barrier per step (parity-buffered slots)
      float4 s0 = sl[p][0], s1 = sl[p][1], s2 = sl[p][2], s3 = sl[p][3];
      int i0 = siw[p][0], i1 = siw[p][1], i2 = siw[p][2], i3 = siw[p][3];
      float gv = s0.x, gx = s0.y, gy = s0.z, gz = s0.w;
      int gi = i0;
      bool bt;
      bt = (s1.x > gv) || (s1.x == gv && i1 < gi);
      if (bt) { gv = s1.x; gi = i1; gx = s1.y; gy = s1.z; gz = s1.w; }
      bt = (s2.x > gv) || (s2.x == gv && i2 < gi);
      if (bt) { gv = s2.x; gi = i2; gx = s2.y; gy = s2.z; gz = s2.w; }
      bt = (s3.x > gv) || (s3.x == gv && i3 < gi);
      if (bt) { gv = s3.x; gi = i3; gx = s3.y; gy = s3.z; gz = s3.w; }
      cur = gi; cx = gx; cy = gy; cz = gz;
    }
  } else {
    const int w = blockIdx.x - 8;  // 0..NW-1
    // ---- phase A: conv tiles, grid-stride (R8-validated math) ----
    // Z[b][n][o] = sum_c F[b][c][n] * W[o][c]
    {
      float (*Bs)[68] = (float(*)[68])smem;          // [128][68]
      float (*As)[68] = (float(*)[68])(smem + 8704); // [32][68]
      const int tid = threadIdx.x;
      const int tx = tid & 15, ty = tid >> 4;
      for (int tile = w; tile < 2048; tile += NW) {
        __syncthreads();  // prev tile's As/Bs readers done before refill
        const int n0 = (tile & 63) * 64;
        const int o0 = ((tile >> 6) & 3) * 64;
        const int bb = tile >> 8;
        for (int l = 0; l < 32; ++l) {
          int e = l * 256 + tid;
          int c = e & 127, oo = e >> 7;
          Bs[c][oo] = W[(o0 + oo) * CIN + c];
        }
        float acc[4][4] = {};
        const float* Fb = F + bb * CIN * N_PTS;
        for (int c0 = 0; c0 < CIN; c0 += 32) {
          __syncthreads();
          for (int l = 0; l < 8; ++l) {
            int e = l * 256 + tid;
            int nn = e & 63, cc = e >> 6;
            As[cc][nn] = Fb[(c0 + cc) * N_PTS + n0 + nn];
          }
          __syncthreads();
#pragma unroll
          for (int cc = 0; cc < 32; ++cc) {
            float4 a = *(const float4*)&As[cc][tx * 4];
            float4 w4 = *(const float4*)&Bs[c0 + cc][ty * 4];
            acc[0][0] += a.x * w4.x; acc[0][1] += a.x * w4.y; acc[0][2] += a.x * w4.z; acc[0][3] += a.x * w4.w;
            acc[1][0] += a.y * w4.x; acc[1][1] += a.y * w4.y; acc[1][2] += a.y * w4.z; acc[1][3] += a.y * w4.w;
            acc[2][0] += a.z * w4.x; acc[2][1] += a.z * w4.y; acc[2][2] += a.z * w4.z; acc[2][3] += a.z * w4.w;
            acc[3][0] += a.w * w4.x; acc[3][1] += a.w * w4.y; acc[3][2] += a.w * w4.z; acc[3][3] += a.w * w4.w;
          }
        }
        float* Zb = Z + (size_t)(bb * N_PTS + n0) * COUT + o0;
#pragma unroll
        for (int i2 = 0; i2 < 4; ++i2) {
          int nn = tx * 4 + i2;
          float4 v = make_float4(acc[i2][0], acc[i2][1], acc[i2][2], acc[i2][3]);
          *(float4*)&Zb[(size_t)nn * COUT + ty * 4] = v;
        }
      }
    }
    // ONE-TIME Z handoff (off the FPS critical path): barrier drains each
    // wave's Z stores (vmcnt(0)); release-add writes back this XCD's L2 so Z
    // is agent-visible; consumers below acquire-invalidate ONCE.
    // gdone lives in the 0xFF-memset region: init -1, full count = NW-1.
    __syncthreads();
    if (threadIdx.x == 0)
      __hip_atomic_fetch_add(gdone, 1, __ATOMIC_RELEASE,
                             __HIP_MEMORY_SCOPE_AGENT);
    if (threadIdx.x == 0) {
      while (__hip_atomic_load(gdone, __ATOMIC_ACQUIRE,
                               __HIP_MEMORY_SCOPE_AGENT) < NW - 1)
        __builtin_amdgcn_s_sleep(16);
    }
    __syncthreads();
    __builtin_amdgcn_fence(__ATOMIC_ACQUIRE, "agent");  // Z now coherent
    // ---- phase B: ballq + gather/max/BN/ReLU, grid-stride ----
    // Per-tile gate: poll the needed fps_idx entries (relaxed agent loads,
    // sc1 from MALL; NO fence, NO L2 invalidation -> xyz/Z stay L2-hot).
    const int lane = threadIdx.x & 63, wv = threadIdx.x >> 6;
    const int o = threadIdx.x;  // 0..255
    const float sc = gamma[o] * (1.0f / sqrtf(rvar[o] + 1e-5f));
    const float bo = bias[o], mo = rmean[o], bt = beta[o];
    float (*T)[9] = (float(*)[9])smem;        // [256][9] floats
    int* sidx = (int*)(smem + 2304);          // [8*NS]
    int* cctr = (int*)(smem + 2816);          // [8] center indices
    for (int tb = w; tb < NTILE_T; tb += NW) {
      if (tb < NTILE_N) {
        // ======== normal 8-center tile (R2-validated path) ========
        const int b = tb & 7;
        const int m0 = (tb >> 3) * 8;
        if (threadIdx.x == 0) {
          int got;
          do {
            got = 1;
#pragma unroll
            for (int c = 0; c < 8; ++c) {
              int v = __hip_atomic_load(fps_idx + b * M_OUT + m0 + c,
                                        __ATOMIC_RELAXED,
                                        __HIP_MEMORY_SCOPE_AGENT);
              cctr[c] = v;
              got &= (v != -1);
            }
            if (!got) __builtin_amdgcn_s_sleep(8);
          } while (!got);
        }
        __syncthreads();  // broadcast cctr; orders prev tile's T/sidx reuse
        const float* base = xyz + b * N_PTS * 3;
        {
#pragma clang fp contract(off)
          for (int c = wv; c < 8; c += 4) {
            const int cidx = cctr[c];
            const float cx = base[cidx * 3 + 0], cy = base[cidx * 3 + 1],
                        cz = base[cidx * 3 + 2];
            int* srow = sidx + c * NS;
            int cnt = 0, first = 0;
            for (int ch = 0; ch < N_PTS / 64 && cnt < NS; ++ch) {
              const int n = ch * 64 + lane;
              float dx = base[n * 3 + 0] - cx;
              float dy = base[n * 3 + 1] - cy;
              float dz = base[n * 3 + 2] - cz;
              float d = dx * dx + dy * dy;
              d = d + dz * dz;
              const bool inb = d < 0.1024f;  // f32(RADIUS^2)
              unsigned long long mask = __ballot(inb);
              if (cnt == 0 && mask) first = ch * 64 + (__ffsll(mask) - 1);
              const int pos = cnt + __popcll(mask & ((1ull << lane) - 1ull));
              if (inb && pos < NS) srow[pos] = n;
              cnt += (int)__popcll(mask);
            }
            if (lane >= cnt) srow[lane] = first;  // pad (center => cnt >= 1)
          }
        }
        __syncthreads();
        const float* Zb = Z + (size_t)b * N_PTS * COUT;
        for (int mi = 0; mi < 8; ++mi) {
          float c0 = -1e30f, c1 = -1e30f, c2 = -1e30f, c3 = -1e30f;
          float c4 = -1e30f, c5 = -1e30f, c6 = -1e30f, c7 = -1e30f;
#pragma unroll
          for (int s = 0; s < NS; s += 8) {
            int4 iv0 = *(const int4*)&sidx[mi * NS + s];
            int4 iv1 = *(const int4*)&sidx[mi * NS + s + 4];
            c0 = fmaxf(c0, Zb[(size_t)iv0.x * COUT + o]);
            c1 = fmaxf(c1, Zb[(size_t)iv0.y * COUT + o]);
            c2 = fmaxf(c2, Zb[(size_t)iv0.z * COUT + o]);
            c3 = fmaxf(c3, Zb[(size_t)iv0.w * COUT + o]);
            c4 = fmaxf(c4, Zb[(size_t)iv1.x * COUT + o]);
            c5 = fmaxf(c5, Zb[(size_t)iv1.y * COUT + o]);
            c6 = fmaxf(c6, Zb[(size_t)iv1.z * COUT + o]);
            c7 = fmaxf(c7, Zb[(size_t)iv1.w * COUT + o]);
          }
          float best = fmaxf(fmaxf(fmaxf(c0, c1), fmaxf(c2, c3)),
                             fmaxf(fmaxf(c4, c5), fmaxf(c6, c7)));
          float tv = best + bo;
          tv = (tv - mo) * sc + bt;
          T[o][mi] = fmaxf(tv, 0.0f);  // distinct (o,mi): race-free
        }
        __syncthreads();
        for (int l = 0; l < 8; ++l) {
          int e = l * 256 + (int)threadIdx.x;
          int mm = e & 7, oo = e >> 3;
          out[(size_t)(b * COUT + oo) * M_OUT + m0 + mm] = T[oo][mm];
        }
      } else {
        // ======== endgame single-center tile (tail de-latencied) ========
        const int k = tb - NTILE_N;     // 0..511
        const int b = k & 7;
        const int m = 960 + (k >> 3);   // 960..1023
        if (threadIdx.x == 0) {
          int v;
          while ((v = __hip_atomic_load(fps_idx + b * M_OUT + m,
                                        __ATOMIC_RELAXED,
                                        __HIP_MEMORY_SCOPE_AGENT)) == -1)
            __builtin_amdgcn_s_sleep(2);  // fine wake: this IS the tail
          cctr[0] = v;
        }
        __syncthreads();  // broadcast; also orders prev tile's sidx reuse
        const float* base = xyz + b * N_PTS * 3;
        if (wv == 0) {  // identical per-center scan, wave 0 only
#pragma clang fp contract(off)
          const int cidx = cctr[0];
          const float cx = base[cidx * 3 + 0], cy = base[cidx * 3 + 1],
                      cz = base[cidx * 3 + 2];
          int cnt = 0, first = 0;
          for (int ch = 0; ch < N_PTS / 64 && cnt < NS; ++ch) {
            const int n = ch * 64 + lane;
            float dx = base[n * 3 + 0] - cx;
            float dy = base[n * 3 + 1] - cy;
            float dz = base[n * 3 + 2] - cz;
            float d = dx * dx + dy * dy;
            d = d + dz * dz;
            const bool inb = d < 0.1024f;  // f32(RADIUS^2)
            unsigned long long mask = __ballot(inb);
            if (cnt == 0 && mask) first = ch * 64 + (__ffsll(mask) - 1);
            const int pos = cnt + __popcll(mask & ((1ull << lane) - 1ull));
            if (inb && pos < NS) sidx[pos] = n;
            cnt += (int)__popcll(mask);
          }
          if (lane >= cnt) sidx[lane] = first;  // pad (center => cnt >= 1)
        }
        __syncthreads();
        // pool: identical 8-chain structure per (o, m) => bit-identical
        const float* Zb = Z + (size_t)b * N_PTS * COUT;
        float c0 = -1e30f, c1 = -1e30f, c2 = -1e30f, c3 = -1e30f;
        float c4 = -1e30f, c5 = -1e30f, c6 = -1e30f, c7 = -1e30f;
#pragma unroll
        for (int s = 0; s < NS; s += 8) {
          int4 iv0 = *(const int4*)&sidx[s];
          int4 iv1 = *(const int4*)&sidx[s + 4];
          c0 = fmaxf(c0, Zb[(size_t)iv0.x * COUT + o]);
          c1 = fmaxf(c1, Zb[(size_t)iv0.y * COUT + o]);
          c2 = fmaxf(c2, Zb[(size_t)iv0.z * COUT + o]);
          c3 = fmaxf(c3, Zb[(size_t)iv0.w * COUT + o]);
          c4 = fmaxf(c4, Zb[(size_t)iv1.x * COUT + o]);
          c5 = fmaxf(c5, Zb[(size_t)iv1.y * COUT + o]);
          c6 = fmaxf(c6, Zb[(size_t)iv1.z * COUT + o]);
          c7 = fmaxf(c7, Zb[(size_t)iv1.w * COUT + o]);
        }
        float best = fmaxf(fmaxf(fmaxf(c0, c1), fmaxf(c2, c3)),
                           fmaxf(fmaxf(c4, c5), fmaxf(c6, c7)));
        float tv = best + bo;
        tv = (tv - mo) * sc + bt;
        out[(size_t)(b * COUT + o) * M_OUT + m] = fmaxf(tv, 0.0f);
      }
    }
  }
}

extern "C" void kernel_launch(void* const* d_in, const int* in_sizes, int n_in,
                              void* d_out, int out_size, void* d_ws, size_t ws_size,
                              hipStream_t stream) {
  const float* xyz      = (const float*)d_in[0];
  const float* features = (const float*)d_in[1];
  const float* W        = (const float*)d_in[2];
  const float* bias     = (const float*)d_in[3];
  const float* gamma    = (const float*)d_in[4];
  const float* beta     = (const float*)d_in[5];
  const float* rmean    = (const float*)d_in[6];
  const float* rvar     = (const float*)d_in[7];
  float* out = (float*)d_out;

  char* ws = (char*)d_ws;
  int* fps   = (int*)ws;                                 // 32 KB
  int* gdone = (int*)(ws + (32 << 10));                  // inside 0xFF region
  float* Z   = (float*)(ws + (64 << 10) + (2 << 20));    // 33.5 MB

  // ONE memset node: fps_idx sentinel (-1 = unpublished) AND gdone (-1;
  // complete when it reaches NW-1). Graph replays re-execute it, so no
  // stale-state hazard even if the workspace is poisoned between runs.
  hipMemsetAsync(ws, 0xFF, (32 << 10) + 64, stream);
  fused_kernel<<<8 + NW, 256, 0, stream>>>(
      xyz, fps, gdone, features, W, Z, bias, gamma, beta, rmean, rvar, out);
}